// Round 12
// baseline (145.799 us; speedup 1.0000x reference)
//
#include <hip/hip_runtime.h>
#include <hip/hip_bf16.h>
#include <hip/hip_cooperative_groups.h>

// SEQ=512, BATCH=64, DIM=512, MAXLEN=512, E=655360
// out[b][u][s] = edge(b,u,s) ? exp(scale) / (T_e + 1e-10*(T-T_e)) : 0  (max cancels)
// scale[s,b,m] = sum_d M[s,b,d] * W[m,d]
//
// Byte-minimal structure: block = (b, s-tile 128) x FULL m=512 -> M f32 read
// ONCE chip-wide (67 MB); W (bf16, 0.5 MB) is the re-read operand (L2-hot).
// grid = 256 = 1 block/CU, cooperative: partials -> grid.sync -> scale in-reg.
// K-loop: 3-deep global_load_lds ring, counted vmcnt(12), raw barriers.

#define SEQ 512
#define BATCH 64
#define DIM 512
#define MAXLEN 512

namespace cg = cooperative_groups;

typedef __attribute__((ext_vector_type(8))) __bf16 bf16x8;
typedef __attribute__((ext_vector_type(4))) float f32x4;

__device__ __forceinline__ unsigned cvt_pk(float lo, float hi) {
    unsigned r;
    asm("v_cvt_pk_bf16_f32 %0, %1, %2" : "=v"(r) : "v"(lo), "v"(hi));
    return r;
}

__device__ __forceinline__ void gload16(const void* g, void* l) {
    __builtin_amdgcn_global_load_lds(
        (const __attribute__((address_space(1))) void*)g,
        (__attribute__((address_space(3))) void*)l, 16, 0, 0);
}

// ---------------- edge bitmap scatter ----------------
__global__ __launch_bounds__(256) void edge_scatter(const int* __restrict__ eb,
                                                    const int* __restrict__ eu,
                                                    const int* __restrict__ ev,
                                                    unsigned int* __restrict__ bits,
                                                    int E) {
    int i = blockIdx.x * 256 + threadIdx.x;
    if (i < E) {
        int b = eb[i], u = eu[i], v = ev[i];
        atomicOr(&bits[(b * MAXLEN + u) * 16 + (v >> 5)], 1u << (v & 31));
    }
}

// ---------------- W f32 -> bf16 (1 MB -> 0.5 MB, once) ----------------
__global__ __launch_bounds__(256) void cvt_w(const float* __restrict__ src,
                                             unsigned short* __restrict__ dst) {
    int i = blockIdx.x * 256 + threadIdx.x;   // 32768 threads x 8 floats
    const float4* s = (const float4*)src + (size_t)i * 2;
    float4 a = s[0], c = s[1];
    uint4 o;
    o.x = cvt_pk(a.x, a.y); o.y = cvt_pk(a.z, a.w);
    o.z = cvt_pk(c.x, c.y); o.w = cvt_pk(c.z, c.w);
    ((uint4*)dst)[i] = o;
}

// ---------------- main kernel (MODE 1 = cooperative, 0 = two-phase) ----------------
template <int COOP>
__global__ __launch_bounds__(512, 2) void fused_big(
    const float* __restrict__ Mg,
    const unsigned short* __restrict__ Wbf,
    const unsigned int* __restrict__ bitsG,
    float2* __restrict__ Gpart,
    float* __restrict__ out) {
    // LDS 147456 B:
    //   ringA [0, 98304):      3 slots x (512 m-rows x 64 B bf16 K32);
    //                          LDS chunk c of row r = src chunk c^((r>>1)&3)
    //   ringB [98304, 147456): 3 slots x (128 s-rows x 128 B f32 K32);
    //                          LDS chunk c of row r = src chunk c^(r&7)
    //   overlays after K-loop: redL float2[512][2] at +98304; invL f32[512] at +114688
    __shared__ __align__(16) char lds[147456];

    const int blk = blockIdx.x;
    const int work = (blk & 7) * 32 + (blk >> 3);   // bijective [0,256): b's 4 tiles -> 1 XCD
    const int b  = work >> 2;
    const int st = work & 3;
    const int s0 = st * 128;

    const int t = threadIdx.x, lane = t & 63, wv = t >> 6;
    const int wm = wv >> 1;      // 0..3: m-rows wm*128..+127
    const int ws = wv & 1;       // 0..1: s-cols ws*64..+63
    const int lg = lane >> 4, lc = lane & 15;

    // ---- DMA lane sources (swizzle folded into source address) ----
    const int arow = wv * 64 + (lane >> 2);                 // +q*16
    const int acs  = (lane & 3) ^ ((lane >> 3) & 3);
    const char* const asrc = (const char*)Wbf + (size_t)arow * 1024 + acs * 16;
    char* const aDst = lds + wv * 4096;                     // +slot*32768 +q*1024

    const int brow = s0 + wv * 16 + (lane >> 3);            // +q*8
    const int bcs  = (lane & 7) ^ ((lane >> 3) & 7);
    const char* const bsrc = (const char*)Mg + ((size_t)brow * BATCH + b) * 2048 + bcs * 16;
    char* const bDst = lds + 98304 + wv * 2048;             // +slot*16384 +q*1024

    // prologue: issue steps 0,1,2 (6 insts/wave each)
#pragma unroll
    for (int p = 0; p < 3; ++p) {
#pragma unroll
        for (int q = 0; q < 4; ++q)
            gload16(asrc + q * 16384 + p * 64, aDst + p * 32768 + q * 1024);
#pragma unroll
        for (int q = 0; q < 2; ++q)
            gload16(bsrc + ((size_t)q << 20) + p * 128, bDst + p * 16384 + q * 1024);
    }

    f32x4 acc[8][4] = {};
    const int aswz = (lc >> 1) & 3;
    const int bswz = lc & 7;

#pragma unroll
    for (int ks = 0; ks < 16; ++ks) {
        if (ks <= 13)      asm volatile("s_waitcnt vmcnt(12)" ::: "memory");
        else if (ks == 14) asm volatile("s_waitcnt vmcnt(6)" ::: "memory");
        else               asm volatile("s_waitcnt vmcnt(0)" ::: "memory");
        __builtin_amdgcn_s_barrier();   // all waves' step-ks data landed

        const int sl = ks % 3;
        bf16x8 bfr[4];
#pragma unroll
        for (int j = 0; j < 4; ++j) {
            const char* p = lds + 98304 + sl * 16384 + (ws * 64 + j * 16 + lc) * 128;
            f32x4 x = *(const f32x4*)(p + (((2 * lg) ^ bswz) * 16));
            f32x4 y = *(const f32x4*)(p + (((2 * lg + 1) ^ bswz) * 16));
            uint4 pk;
            pk.x = cvt_pk(x[0], x[1]); pk.y = cvt_pk(x[2], x[3]);
            pk.z = cvt_pk(y[0], y[1]); pk.w = cvt_pk(y[2], y[3]);
            bfr[j] = __builtin_bit_cast(bf16x8, pk);
        }
        __builtin_amdgcn_s_setprio(1);
#pragma unroll
        for (int i = 0; i < 8; ++i) {
            bf16x8 af = *(const bf16x8*)(lds + sl * 32768
                        + (wm * 128 + i * 16 + lc) * 64 + ((lg ^ aswz) * 16));
#pragma unroll
            for (int j = 0; j < 4; ++j)
                acc[i][j] = __builtin_amdgcn_mfma_f32_16x16x32_bf16(af, bfr[j], acc[i][j], 0, 0, 0);
        }
        __builtin_amdgcn_s_setprio(0);
        __builtin_amdgcn_sched_barrier(0);
        __builtin_amdgcn_s_barrier();   // all waves done reading slot sl
        if (ks + 3 < 16) {
#pragma unroll
            for (int q = 0; q < 4; ++q)
                gload16(asrc + q * 16384 + (ks + 3) * 64, aDst + sl * 32768 + q * 1024);
#pragma unroll
            for (int q = 0; q < 2; ++q)
                gload16(bsrc + ((size_t)q << 20) + (ks + 3) * 128, bDst + sl * 16384 + q * 1024);
        }
    }

    // ---- pass 1: exp + masked/unmasked row-partials over this block's 128 s ----
    float2* const redL = (float2*)(lds + 98304);   // [512][2]
#pragma unroll
    for (int i = 0; i < 8; ++i) {
#pragma unroll
        for (int r = 0; r < 4; ++r) {
            const int row = wm * 128 + i * 16 + lg * 4 + r;
            const uint2 wbt = *(const uint2*)(bitsG + (size_t)(b * MAXLEN + row) * 16 + st * 4 + ws * 2);
            float T = 0.f, Te = 0.f;
#pragma unroll
            for (int j = 0; j < 4; ++j) {
                float e = __expf(acc[i][j][r]);
                acc[i][j][r] = e;
                unsigned word = (j & 2) ? wbt.y : wbt.x;
                float bit = (float)((word >> ((j & 1) * 16 + lc)) & 1u);
                T += e; Te += e * bit;
            }
#pragma unroll
            for (int off = 1; off < 16; off <<= 1) {
                T  += __shfl_xor(T, off);
                Te += __shfl_xor(Te, off);
            }
            if (lc == 0) redL[row * 2 + ws] = make_float2(T, Te);
        }
    }
    __syncthreads();
    {
        float2 p0 = redL[t * 2], p1 = redL[t * 2 + 1];
        Gpart[(size_t)(b * 4 + st) * 512 + t] = make_float2(p0.x + p1.x, p0.y + p1.y);
    }

    if constexpr (COOP) {
        cg::this_grid().sync();
        // denominators for all 512 rows of this b
        float* const invL = (float*)(lds + 114688);
        {
            float2 q0 = Gpart[(size_t)(b * 4 + 0) * 512 + t];
            float2 q1 = Gpart[(size_t)(b * 4 + 1) * 512 + t];
            float2 q2 = Gpart[(size_t)(b * 4 + 2) * 512 + t];
            float2 q3 = Gpart[(size_t)(b * 4 + 3) * 512 + t];
            float T  = q0.x + q1.x + q2.x + q3.x;
            float Te = q0.y + q1.y + q2.y + q3.y;
            invL[t] = 1.0f / (Te + 1e-10f * (T - Te));
        }
        __syncthreads();
#pragma unroll
        for (int i = 0; i < 8; ++i) {
#pragma unroll
            for (int r = 0; r < 4; ++r) {
                const int row = wm * 128 + i * 16 + lg * 4 + r;
                const float inv = invL[row];
                const uint2 wbt = *(const uint2*)(bitsG + (size_t)(b * MAXLEN + row) * 16 + st * 4 + ws * 2);
                size_t base = ((size_t)(b * MAXLEN + row)) * SEQ + s0 + ws * 64 + lc;
#pragma unroll
                for (int j = 0; j < 4; ++j) {
                    unsigned word = (j & 2) ? wbt.y : wbt.x;
                    unsigned bit = (word >> ((j & 1) * 16 + lc)) & 1u;
                    out[base + j * 16] = bit ? acc[i][j][r] * inv : 0.0f;
                }
            }
        }
    } else {
        // two-phase fallback: write raw exp values; rescale kernel finishes
#pragma unroll
        for (int i = 0; i < 8; ++i) {
#pragma unroll
            for (int r = 0; r < 4; ++r) {
                const int row = wm * 128 + i * 16 + lg * 4 + r;
                size_t base = ((size_t)(b * MAXLEN + row)) * SEQ + s0 + ws * 64 + lc;
#pragma unroll
                for (int j = 0; j < 4; ++j)
                    out[base + j * 16] = acc[i][j][r];
            }
        }
    }
}

// ---------------- fallback phase 2: mask + renorm in place ----------------
__global__ __launch_bounds__(256) void rescale(const unsigned int* __restrict__ bitsG,
                                               const float2* __restrict__ Gpart,
                                               float* __restrict__ out) {
    // block = 16 rows; thread: row = blk*16 + (t>>4), cols (t&15)*32..+31
    const int t = threadIdx.x;
    const int row = blockIdx.x * 16 + (t >> 4);      // global (b*512+u)
    const int b = row >> 9;
    const int cw = t & 15;                            // 32-col word index
    float2 q0 = Gpart[(size_t)(b * 4 + 0) * 512 + (row & 511)];
    float2 q1 = Gpart[(size_t)(b * 4 + 1) * 512 + (row & 511)];
    float2 q2 = Gpart[(size_t)(b * 4 + 2) * 512 + (row & 511)];
    float2 q3 = Gpart[(size_t)(b * 4 + 3) * 512 + (row & 511)];
    float T  = q0.x + q1.x + q2.x + q3.x;
    float Te = q0.y + q1.y + q2.y + q3.y;
    const float inv = 1.0f / (Te + 1e-10f * (T - Te));
    const unsigned word = bitsG[(size_t)row * 16 + cw];
    float* rp = out + (size_t)row * SEQ + cw * 32;
#pragma unroll
    for (int h = 0; h < 8; ++h) {
        float4 v = *(float4*)(rp + h * 4);
        v.x = ((word >> (h * 4 + 0)) & 1u) ? v.x * inv : 0.0f;
        v.y = ((word >> (h * 4 + 1)) & 1u) ? v.y * inv : 0.0f;
        v.z = ((word >> (h * 4 + 2)) & 1u) ? v.z * inv : 0.0f;
        v.w = ((word >> (h * 4 + 3)) & 1u) ? v.w * inv : 0.0f;
        *(float4*)(rp + h * 4) = v;
    }
}

// ---------------- launch ----------------
extern "C" void kernel_launch(void* const* d_in, const int* in_sizes, int n_in,
                              void* d_out, int out_size, void* d_ws, size_t ws_size,
                              hipStream_t stream) {
    const float* Mg = (const float*)d_in[0];
    const float* Wg = (const float*)d_in[1];
    // d_in[2] = lengths (unused by reference)
    const int* eb = (const int*)d_in[3];
    const int* eu = (const int*)d_in[4];
    const int* ev = (const int*)d_in[5];
    const int E = in_sizes[3];

    float* out = (float*)d_out;
    unsigned int* bits = (unsigned int*)d_ws;                          // 2 MB
    unsigned short* Wbf = (unsigned short*)((char*)d_ws + 2097152);    // 0.5 MB
    float2* Gpart = (float2*)((char*)d_ws + 2097152 + 524288);         // 1 MB

    (void)hipMemsetAsync(bits, 0, (size_t)BATCH * MAXLEN * 16 * sizeof(unsigned int), stream);
    edge_scatter<<<(E + 255) / 256, 256, 0, stream>>>(eb, eu, ev, bits, E);
    cvt_w<<<128, 256, 0, stream>>>(Wg, Wbf);

    const float* MgA = Mg;
    const unsigned short* WbfA = Wbf;
    const unsigned int* bitsA = bits;
    float2* GpartA = Gpart;
    float* outA = out;
    void* args[] = {(void*)&MgA, (void*)&WbfA, (void*)&bitsA, (void*)&GpartA, (void*)&outA};
    hipError_t e = hipLaunchCooperativeKernel(
        reinterpret_cast<void*>(fused_big<1>), dim3(256), dim3(512), args, 0, stream);
    if (e != hipSuccess) {
        fused_big<0><<<256, 512, 0, stream>>>(Mg, Wbf, bits, Gpart, out);
        rescale<<<2048, 256, 0, stream>>>(bits, Gpart, out);
    }
}

// Round 13
// 113.815 us; speedup vs baseline: 1.2810x; 1.2810x over previous
//
#include <hip/hip_runtime.h>
#include <hip/hip_bf16.h>

// SEQ=512, BATCH=64, DIM=512, MAXLEN=512, E=655360
// out[b][u][s] = edge(b,u,s) ? exp(scale) / (T_e + 1e-10*(T-T_e)) : 0  (max cancels)
// scale[s,b,m] = sum_d M[s,b,d] * W[m,d]
//
// Occupancy-first: 1024 blocks of 256 thr / 32 KB LDS -> 3 blocks/CU (12 waves),
// independent barrier groups overlap each other's stalls. 128x128 tile, BK=32,
// double-buffered, reg-staged f32->bf16 (no prep pass), T14 issue-early.
// Epilogue: exp + atomicAdd row (T,Te) + masked-exp written via LDS transpose
// (full-line stores). rescale pass: out *= 1/(Te+1e-10(T-Te)) per row.

#define SEQ 512
#define BATCH 64
#define DIM 512
#define MAXLEN 512

typedef __attribute__((ext_vector_type(8))) __bf16 bf16x8;
typedef __attribute__((ext_vector_type(4))) float f32x4;

__device__ __forceinline__ unsigned cvt_pk(float lo, float hi) {
    unsigned r;
    asm("v_cvt_pk_bf16_f32 %0, %1, %2" : "=v"(r) : "v"(lo), "v"(hi));
    return r;
}

// ---------------- edge bitmap scatter ----------------
__global__ __launch_bounds__(256) void edge_scatter(const int* __restrict__ eb,
                                                    const int* __restrict__ eu,
                                                    const int* __restrict__ ev,
                                                    unsigned int* __restrict__ bits,
                                                    int E) {
    int i = blockIdx.x * 256 + threadIdx.x;
    if (i < E) {
        int b = eb[i], u = eu[i], v = ev[i];
        atomicOr(&bits[(b * MAXLEN + u) * 16 + (v >> 5)], 1u << (v & 31));
    }
}

// ---------------- GEMM + exp + row-partial atomics ----------------
__global__ __launch_bounds__(256, 3) void gemm_exp(
    const float* __restrict__ Mg,
    const float* __restrict__ Wg,
    const unsigned int* __restrict__ bitsG,
    float* __restrict__ Gpart,
    float* __restrict__ out) {
    // LDS 32 KB: Ab[buf] at buf*8192 (128 rows x 64B bf16), Bb[buf] at 16384+buf*8192.
    // Row r phys chunk p (16B) holds src k-chunk p ^ ((r>>1)&3).
    // Epilogue overlays (region [0,16384)): red float2[128][2]; stg f32[16][132].
    __shared__ __align__(16) char lds[32768];

    const int g = blockIdx.x;
    const int work = (g & 7) * 128 + (g >> 3);   // bijective [0,1024): same-b -> one XCD
    const int b  = work >> 4;
    const int m0 = ((work >> 2) & 3) * 128;
    const int s0 = (work & 3) * 128;

    const int t = threadIdx.x, lane = t & 63, wv = t >> 6;
    const int wm = wv >> 1, ws = wv & 1;
    const int lg = lane >> 4, lc = lane & 15;

    // staging map: thread owns chunks (r0, p0) and (r0+64, p0); src chunk = p0^swz(r)
    const int r0 = t >> 2, p0 = t & 3;
    const int ca = p0 ^ ((r0 >> 1) & 3);        // same for r0 and r0+64
    const float* const aS0 = Wg + (size_t)(m0 + r0) * DIM + ca * 8;
    const float* const aS1 = Wg + (size_t)(m0 + r0 + 64) * DIM + ca * 8;
    const float* const bS0 = Mg + ((size_t)(s0 + r0) * BATCH + b) * DIM + ca * 8;
    const float* const bS1 = Mg + ((size_t)(s0 + r0 + 64) * BATCH + b) * DIM + ca * 8;
    char* const aD0 = lds + r0 * 64 + p0 * 16;
    char* const aD1 = lds + (r0 + 64) * 64 + p0 * 16;
    char* const bD0 = lds + 16384 + r0 * 64 + p0 * 16;
    char* const bD1 = lds + 16384 + (r0 + 64) * 64 + p0 * 16;

    float4 A0a, A0b, A1a, A1b, B0a, B0b, B1a, B1b;
#define LOADSTEP(k0)                                                        \
    {                                                                       \
        A0a = *(const float4*)(aS0 + (k0));  A0b = *(const float4*)(aS0 + (k0) + 4); \
        A1a = *(const float4*)(aS1 + (k0));  A1b = *(const float4*)(aS1 + (k0) + 4); \
        B0a = *(const float4*)(bS0 + (k0));  B0b = *(const float4*)(bS0 + (k0) + 4); \
        B1a = *(const float4*)(bS1 + (k0));  B1b = *(const float4*)(bS1 + (k0) + 4); \
    }
#define WRITESTEP(buf)                                                      \
    {                                                                       \
        uint4 v;                                                            \
        v.x = cvt_pk(A0a.x, A0a.y); v.y = cvt_pk(A0a.z, A0a.w);             \
        v.z = cvt_pk(A0b.x, A0b.y); v.w = cvt_pk(A0b.z, A0b.w);             \
        *(uint4*)(aD0 + (buf) * 8192) = v;                                  \
        v.x = cvt_pk(A1a.x, A1a.y); v.y = cvt_pk(A1a.z, A1a.w);             \
        v.z = cvt_pk(A1b.x, A1b.y); v.w = cvt_pk(A1b.z, A1b.w);             \
        *(uint4*)(aD1 + (buf) * 8192) = v;                                  \
        v.x = cvt_pk(B0a.x, B0a.y); v.y = cvt_pk(B0a.z, B0a.w);             \
        v.z = cvt_pk(B0b.x, B0b.y); v.w = cvt_pk(B0b.z, B0b.w);             \
        *(uint4*)(bD0 + (buf) * 8192) = v;                                  \
        v.x = cvt_pk(B1a.x, B1a.y); v.y = cvt_pk(B1a.z, B1a.w);             \
        v.z = cvt_pk(B1b.x, B1b.y); v.w = cvt_pk(B1b.z, B1b.w);             \
        *(uint4*)(bD1 + (buf) * 8192) = v;                                  \
    }

    LOADSTEP(0)
    WRITESTEP(0)

    f32x4 acc[4][4] = {};
    const int swz = (lc >> 1) & 3;

#pragma unroll
    for (int ks = 0; ks < 16; ++ks) {
        const int cur = ks & 1;
        __syncthreads();                      // buf[cur] staged & visible
        if (ks < 15) LOADSTEP((ks + 1) * 32)  // in flight under frags+MFMA (T14)

        bf16x8 af[4], bfr[4];
#pragma unroll
        for (int i = 0; i < 4; ++i)
            af[i] = *(const bf16x8*)(lds + cur * 8192
                     + (wm * 64 + i * 16 + lc) * 64 + ((lg ^ swz) * 16));
#pragma unroll
        for (int j = 0; j < 4; ++j)
            bfr[j] = *(const bf16x8*)(lds + 16384 + cur * 8192
                     + (ws * 64 + j * 16 + lc) * 64 + ((lg ^ swz) * 16));

        __builtin_amdgcn_s_setprio(1);
#pragma unroll
        for (int i = 0; i < 4; ++i)
#pragma unroll
            for (int j = 0; j < 4; ++j)
                acc[i][j] = __builtin_amdgcn_mfma_f32_16x16x32_bf16(af[i], bfr[j], acc[i][j], 0, 0, 0);
        __builtin_amdgcn_s_setprio(0);

        if (ks < 15) WRITESTEP(cur ^ 1)       // vmcnt waits folded here by compiler
    }
#undef LOADSTEP
#undef WRITESTEP

    // ---- epilogue: exp + (T,Te) partials -> atomics ----
    float2* const red = (float2*)lds;         // [128][2] overlays Ab (safe: last frags from buf1)
    __syncthreads();
#pragma unroll
    for (int i = 0; i < 4; ++i) {
#pragma unroll
        for (int rr = 0; rr < 4; ++rr) {
            const int m = wm * 64 + i * 16 + lg * 4 + rr;
            const size_t grow = (size_t)(b * MAXLEN + m0 + m);
            const uint2 wbt = *(const uint2*)(bitsG + grow * 16 + (s0 >> 5) + ws * 2);
            float T = 0.f, Te = 0.f;
#pragma unroll
            for (int j = 0; j < 4; ++j) {
                float e = __expf(acc[i][j][rr]);
                acc[i][j][rr] = e;
                unsigned word = (j & 2) ? wbt.y : wbt.x;
                float bit = (float)((word >> ((j & 1) * 16 + lc)) & 1u);
                T += e; Te += e * bit;
            }
#pragma unroll
            for (int off = 1; off < 16; off <<= 1) {
                T  += __shfl_xor(T, off);
                Te += __shfl_xor(Te, off);
            }
            if (lc == 0) red[m * 2 + ws] = make_float2(T, Te);
        }
    }
    __syncthreads();
    if (t < 128) {
        float2 x = red[t * 2], y = red[t * 2 + 1];
        float* gp = Gpart + (size_t)(b * MAXLEN + m0 + t) * 2;
        atomicAdd(gp,     x.x + y.x);
        atomicAdd(gp + 1, x.y + y.y);
    }
    __syncthreads();

    // ---- masked exp -> LDS transpose -> full-line stores ----
    float* const stg = (float*)lds;           // [16][132]
    for (int p = 0; p < 8; ++p) {
        if (wm == (p >> 2)) {
            const int i = p & 3;
#pragma unroll
            for (int rr = 0; rr < 4; ++rr) {
                const int m = wm * 64 + i * 16 + lg * 4 + rr;
                const size_t grow = (size_t)(b * MAXLEN + m0 + m);
                const uint2 wbt = *(const uint2*)(bitsG + grow * 16 + (s0 >> 5) + ws * 2);
#pragma unroll
                for (int j = 0; j < 4; ++j) {
                    unsigned word = (j & 2) ? wbt.y : wbt.x;
                    unsigned bit = (word >> ((j & 1) * 16 + lc)) & 1u;
                    stg[(lg * 4 + rr) * 132 + ws * 64 + j * 16 + lc] =
                        bit ? acc[i][j][rr] : 0.0f;
                }
            }
        }
        __syncthreads();
#pragma unroll
        for (int it = 0; it < 2; ++it) {
            int f = it * 256 + t;             // 512 float4 = 16 rows x 128 cols
            int ml = f >> 5;
            int c4 = (f & 31) * 4;
            float4 v = *(const float4*)(stg + ml * 132 + c4);
            *(float4*)(out + ((size_t)(b * MAXLEN + m0 + p * 16 + ml)) * SEQ + s0 + c4) = v;
        }
        __syncthreads();
    }
}

// ---------------- rescale: out *= inv(row), streaming ----------------
__global__ __launch_bounds__(128) void rescale(const float* __restrict__ Gpart,
                                               float* __restrict__ out) {
    const int row = blockIdx.x;               // 0..32767
    const float2 p = *(const float2*)(Gpart + (size_t)row * 2);
    const float inv = 1.0f / (p.y + 1e-10f * (p.x - p.y));
    float4* rp = (float4*)(out + (size_t)row * SEQ);
    float4 v = rp[threadIdx.x];
    v.x *= inv; v.y *= inv; v.z *= inv; v.w *= inv;
    rp[threadIdx.x] = v;
}

// ---------------- launch ----------------
extern "C" void kernel_launch(void* const* d_in, const int* in_sizes, int n_in,
                              void* d_out, int out_size, void* d_ws, size_t ws_size,
                              hipStream_t stream) {
    const float* Mg = (const float*)d_in[0];
    const float* Wg = (const float*)d_in[1];
    // d_in[2] = lengths (unused by reference)
    const int* eb = (const int*)d_in[3];
    const int* eu = (const int*)d_in[4];
    const int* ev = (const int*)d_in[5];
    const int E = in_sizes[3];

    float* out = (float*)d_out;
    unsigned int* bits = (unsigned int*)d_ws;                      // 2 MB
    float* Gpart = (float*)((char*)d_ws + 2097152);                // 256 KB

    (void)hipMemsetAsync(bits, 0, (size_t)BATCH * MAXLEN * 16 * sizeof(unsigned int), stream);
    (void)hipMemsetAsync(Gpart, 0, (size_t)BATCH * MAXLEN * 2 * sizeof(float), stream);
    edge_scatter<<<(E + 255) / 256, 256, 0, stream>>>(eb, eu, ev, bits, E);
    gemm_exp<<<1024, 256, 0, stream>>>(Mg, Wg, bits, Gpart, out);
    rescale<<<BATCH * MAXLEN, 128, 0, stream>>>(Gpart, out);
}